// Round 1
// baseline (4584.463 us; speedup 1.0000x reference)
//
#include <hip/hip_runtime.h>

#define NVV 300000
#define PCNT 500000
#define EPSV 1e-5f

// ---------------------------------------------------------------------------
// K1: global GroupNorm stats for stage 0 over lv [NV,64], 32 groups x 2 ch.
// Each thread owns whole groups (4 consecutive channels = 2 groups) so no
// cross-channel mixing; shfl merges the 4 row-streams per wave; atomics to ws.
// ---------------------------------------------------------------------------
__global__ __launch_bounds__(256) void k_stats0(const float* __restrict__ lv,
                                                float* __restrict__ stats0) {
    const int t = threadIdx.x;
    const int c4 = t & 15;   // float4 index within a row (channels 4*c4..4*c4+3)
    const int sub = t >> 4;  // 16 row streams per block
    float s0 = 0.f, q0 = 0.f, s1 = 0.f, q1 = 0.f;
    for (int r = blockIdx.x * 16 + sub; r < NVV; r += gridDim.x * 16) {
        const float4 v = *(const float4*)(lv + (size_t)r * 64 + c4 * 4);
        s0 += v.x + v.y; q0 += v.x * v.x + v.y * v.y;
        s1 += v.z + v.w; q1 += v.z * v.z + v.w * v.w;
    }
    // merge lanes that share c4 (bits 4,5 of lane differ)
    #pragma unroll
    for (int d = 16; d < 64; d <<= 1) {
        s0 += __shfl_xor(s0, d); q0 += __shfl_xor(q0, d);
        s1 += __shfl_xor(s1, d); q1 += __shfl_xor(q1, d);
    }
    if ((t & 63) < 16) {
        const int g0 = c4 * 2, g1 = c4 * 2 + 1;
        atomicAdd(&stats0[g0 * 2 + 0], s0);
        atomicAdd(&stats0[g0 * 2 + 1], q0);
        atomicAdd(&stats0[g1 * 2 + 0], s1);
        atomicAdd(&stats0[g1 * 2 + 1], q1);
    }
}

// ---------------------------------------------------------------------------
// Finalize: stats sums -> per-channel affine A[k] (scale), B[k] (shift) so the
// apply kernels do xn = relu(v*A + B). C=64 -> 2 ch/group, C=32 -> 1 ch/group.
// ---------------------------------------------------------------------------
__global__ void k_finalize(const float* __restrict__ stats,
                           const float* __restrict__ gw,
                           const float* __restrict__ gb,
                           float* __restrict__ A, float* __restrict__ B,
                           int C, float cntInv) {
    const int k = threadIdx.x;
    if (k >= C) return;
    const int g = (C == 32) ? k : (k >> 1);
    const float s = stats[g * 2], q = stats[g * 2 + 1];
    const float mean = s * cntInv;
    const float var = q * cntInv - mean * mean;
    const float rs = rsqrtf(var + EPSV);
    const float a = rs * gw[k];
    A[k] = a;
    B[k] = gb[k] - mean * a;
}

// ---------------------------------------------------------------------------
// K2: stage0.  Per wave: 64 rows (lane = row).  Fuses:
//   proj = raw lv @ clsW^T           [NV,20]
//   x0   = relu(GN0(lv)) @ W0^T      [NV,64]
//   stats1 accumulation on x0 (for GN1) via wave-reduce + atomics
// Weights indexed uniformly -> scalar loads; 1 v_fmac per MAC.
// ---------------------------------------------------------------------------
__global__ __launch_bounds__(256) void k_stage0(const float* __restrict__ lv,
        const float* __restrict__ W0, const float* __restrict__ clsW,
        const float* __restrict__ A, const float* __restrict__ B,
        float* __restrict__ x0, float* __restrict__ proj,
        float* __restrict__ stats1) {
    const int lane = threadIdx.x & 63;
    const int wv = threadIdx.x >> 6;
    const int row = (blockIdx.x * 4 + wv) * 64 + lane;
    const bool valid = row < NVV;
    const int r = valid ? row : NVV - 1;
    const float* src = lv + (size_t)r * 64;
    float v[64];
    #pragma unroll
    for (int k4 = 0; k4 < 16; ++k4) {
        const float4 t = *(const float4*)(src + k4 * 4);
        v[4 * k4 + 0] = t.x; v[4 * k4 + 1] = t.y;
        v[4 * k4 + 2] = t.z; v[4 * k4 + 3] = t.w;
    }
    // ---- proj on RAW lv ----
    #pragma unroll
    for (int cq = 0; cq < 5; ++cq) {
        float a0 = 0.f, a1 = 0.f, a2 = 0.f, a3 = 0.f;
        #pragma unroll
        for (int k = 0; k < 64; ++k) {
            a0 = fmaf(v[k], clsW[(cq * 4 + 0) * 64 + k], a0);
            a1 = fmaf(v[k], clsW[(cq * 4 + 1) * 64 + k], a1);
            a2 = fmaf(v[k], clsW[(cq * 4 + 2) * 64 + k], a2);
            a3 = fmaf(v[k], clsW[(cq * 4 + 3) * 64 + k], a3);
        }
        if (valid)
            *(float4*)(proj + (size_t)row * 20 + cq * 4) = make_float4(a0, a1, a2, a3);
    }
    // ---- normalize + relu in place ----
    #pragma unroll
    for (int k = 0; k < 64; ++k) v[k] = fmaxf(fmaf(v[k], A[k], B[k]), 0.f);
    // ---- x0 = xn @ W0^T, fused stats1 ----
    #pragma unroll
    for (int jq = 0; jq < 16; ++jq) {
        float a0 = 0.f, a1 = 0.f, a2 = 0.f, a3 = 0.f;
        #pragma unroll
        for (int k = 0; k < 64; ++k) {
            a0 = fmaf(v[k], W0[(jq * 4 + 0) * 64 + k], a0);
            a1 = fmaf(v[k], W0[(jq * 4 + 1) * 64 + k], a1);
            a2 = fmaf(v[k], W0[(jq * 4 + 2) * 64 + k], a2);
            a3 = fmaf(v[k], W0[(jq * 4 + 3) * 64 + k], a3);
        }
        if (valid)
            *(float4*)(x0 + (size_t)row * 64 + jq * 4) = make_float4(a0, a1, a2, a3);
        // channels 4jq..4jq+3 -> groups 2jq (a0,a1), 2jq+1 (a2,a3)
        float sA = valid ? a0 + a1 : 0.f;
        float qA = valid ? a0 * a0 + a1 * a1 : 0.f;
        float sB = valid ? a2 + a3 : 0.f;
        float qB = valid ? a2 * a2 + a3 * a3 : 0.f;
        #pragma unroll
        for (int d = 1; d < 64; d <<= 1) {
            sA += __shfl_xor(sA, d); qA += __shfl_xor(qA, d);
            sB += __shfl_xor(sB, d); qB += __shfl_xor(qB, d);
        }
        if (lane == 0) {
            atomicAdd(&stats1[(2 * jq) * 2 + 0], sA);
            atomicAdd(&stats1[(2 * jq) * 2 + 1], qA);
            atomicAdd(&stats1[(2 * jq + 1) * 2 + 0], sB);
            atomicAdd(&stats1[(2 * jq + 1) * 2 + 1], qB);
        }
    }
}

// ---------------------------------------------------------------------------
// K3: stage1.  x1 = relu(GN1(x0)) @ W1^T  [NV,32]; fused stats2 (1 ch/group).
// ---------------------------------------------------------------------------
__global__ __launch_bounds__(256) void k_stage1(const float* __restrict__ x0,
        const float* __restrict__ W1,
        const float* __restrict__ A, const float* __restrict__ B,
        float* __restrict__ x1, float* __restrict__ stats2) {
    const int lane = threadIdx.x & 63;
    const int wv = threadIdx.x >> 6;
    const int row = (blockIdx.x * 4 + wv) * 64 + lane;
    const bool valid = row < NVV;
    const int r = valid ? row : NVV - 1;
    const float* src = x0 + (size_t)r * 64;
    float v[64];
    #pragma unroll
    for (int k4 = 0; k4 < 16; ++k4) {
        const float4 t = *(const float4*)(src + k4 * 4);
        v[4 * k4 + 0] = t.x; v[4 * k4 + 1] = t.y;
        v[4 * k4 + 2] = t.z; v[4 * k4 + 3] = t.w;
    }
    #pragma unroll
    for (int k = 0; k < 64; ++k) v[k] = fmaxf(fmaf(v[k], A[k], B[k]), 0.f);
    #pragma unroll
    for (int jq = 0; jq < 8; ++jq) {
        float a0 = 0.f, a1 = 0.f, a2 = 0.f, a3 = 0.f;
        #pragma unroll
        for (int k = 0; k < 64; ++k) {
            a0 = fmaf(v[k], W1[(jq * 4 + 0) * 64 + k], a0);
            a1 = fmaf(v[k], W1[(jq * 4 + 1) * 64 + k], a1);
            a2 = fmaf(v[k], W1[(jq * 4 + 2) * 64 + k], a2);
            a3 = fmaf(v[k], W1[(jq * 4 + 3) * 64 + k], a3);
        }
        if (valid)
            *(float4*)(x1 + (size_t)row * 32 + jq * 4) = make_float4(a0, a1, a2, a3);
        float s0 = valid ? a0 : 0.f, q0 = valid ? a0 * a0 : 0.f;
        float s1 = valid ? a1 : 0.f, q1 = valid ? a1 * a1 : 0.f;
        float s2 = valid ? a2 : 0.f, q2 = valid ? a2 * a2 : 0.f;
        float s3 = valid ? a3 : 0.f, q3 = valid ? a3 * a3 : 0.f;
        #pragma unroll
        for (int d = 1; d < 64; d <<= 1) {
            s0 += __shfl_xor(s0, d); q0 += __shfl_xor(q0, d);
            s1 += __shfl_xor(s1, d); q1 += __shfl_xor(q1, d);
            s2 += __shfl_xor(s2, d); q2 += __shfl_xor(q2, d);
            s3 += __shfl_xor(s3, d); q3 += __shfl_xor(q3, d);
        }
        if (lane == 0) {
            atomicAdd(&stats2[(jq * 4 + 0) * 2 + 0], s0);
            atomicAdd(&stats2[(jq * 4 + 0) * 2 + 1], q0);
            atomicAdd(&stats2[(jq * 4 + 1) * 2 + 0], s1);
            atomicAdd(&stats2[(jq * 4 + 1) * 2 + 1], q1);
            atomicAdd(&stats2[(jq * 4 + 2) * 2 + 0], s2);
            atomicAdd(&stats2[(jq * 4 + 2) * 2 + 1], q2);
            atomicAdd(&stats2[(jq * 4 + 3) * 2 + 0], s3);
            atomicAdd(&stats2[(jq * 4 + 3) * 2 + 1], q3);
        }
    }
}

// ---------------------------------------------------------------------------
// K4: stage2 (bottleneck).  x2 = relu(GN2(x1)) @ W2^T  [NV,8].
// ---------------------------------------------------------------------------
__global__ __launch_bounds__(256) void k_stage2(const float* __restrict__ x1,
        const float* __restrict__ W2,
        const float* __restrict__ A, const float* __restrict__ B,
        float* __restrict__ x2) {
    const int lane = threadIdx.x & 63;
    const int wv = threadIdx.x >> 6;
    const int row = (blockIdx.x * 4 + wv) * 64 + lane;
    const bool valid = row < NVV;
    const int r = valid ? row : NVV - 1;
    const float* src = x1 + (size_t)r * 32;
    float v[32];
    #pragma unroll
    for (int k4 = 0; k4 < 8; ++k4) {
        const float4 t = *(const float4*)(src + k4 * 4);
        v[4 * k4 + 0] = t.x; v[4 * k4 + 1] = t.y;
        v[4 * k4 + 2] = t.z; v[4 * k4 + 3] = t.w;
    }
    #pragma unroll
    for (int k = 0; k < 32; ++k) v[k] = fmaxf(fmaf(v[k], A[k], B[k]), 0.f);
    #pragma unroll
    for (int jq = 0; jq < 2; ++jq) {
        float a0 = 0.f, a1 = 0.f, a2 = 0.f, a3 = 0.f;
        #pragma unroll
        for (int k = 0; k < 32; ++k) {
            a0 = fmaf(v[k], W2[(jq * 4 + 0) * 32 + k], a0);
            a1 = fmaf(v[k], W2[(jq * 4 + 1) * 32 + k], a1);
            a2 = fmaf(v[k], W2[(jq * 4 + 2) * 32 + k], a2);
            a3 = fmaf(v[k], W2[(jq * 4 + 3) * 32 + k], a3);
        }
        if (valid)
            *(float4*)(x2 + (size_t)row * 8 + jq * 4) = make_float4(a0, a1, a2, a3);
    }
}

// ---------------------------------------------------------------------------
// K5: per-position gather + max-normalize + delta weights + classify via proj.
// out[p,c] = cls_b[c] + sum_v (bary_v + dw_v) * proj[idx_v, c]
// ---------------------------------------------------------------------------
__global__ __launch_bounds__(256) void k_final(const int* __restrict__ idx,
        const float* __restrict__ bary, const float* __restrict__ x2,
        const float* __restrict__ proj, const float* __restrict__ gamma,
        const float* __restrict__ beta, const float* __restrict__ dWw,
        const float* __restrict__ dWb, const float* __restrict__ clsb,
        float* __restrict__ out) {
    const int p = blockIdx.x * 256 + threadIdx.x;
    if (p >= PCNT) return;
    const int4 iv = *(const int4*)(idx + (size_t)p * 4);
    const float4 bv = *(const float4*)(bary + (size_t)p * 4);
    const int ids[4] = {iv.x, iv.y, iv.z, iv.w};
    const float bb[4] = {bv.x, bv.y, bv.z, bv.w};
    float g[4][8];
    #pragma unroll
    for (int vtx = 0; vtx < 4; ++vtx) {
        const float* s = x2 + (size_t)ids[vtx] * 8;
        const float4 u0 = *(const float4*)(s);
        const float4 u1 = *(const float4*)(s + 4);
        g[vtx][0] = u0.x; g[vtx][1] = u0.y; g[vtx][2] = u0.z; g[vtx][3] = u0.w;
        g[vtx][4] = u1.x; g[vtx][5] = u1.y; g[vtx][6] = u1.z; g[vtx][7] = u1.w;
    }
    float sub[9];
    #pragma unroll
    for (int j = 0; j < 8; ++j) {
        const float mx = fmaxf(fmaxf(g[0][j], g[1][j]), fmaxf(g[2][j], g[3][j]));
        sub[j] = fmaf(gamma[j], mx, beta[j]);
    }
    {
        const float mx8 = fmaxf(fmaxf(bb[0], bb[1]), fmaxf(bb[2], bb[3]));
        sub[8] = fmaf(gamma[8], mx8, beta[8]);
    }
    float wv4[4];
    #pragma unroll
    for (int vtx = 0; vtx < 4; ++vtx) {
        float dw = dWb[0];
        #pragma unroll
        for (int j = 0; j < 8; ++j) dw = fmaf(g[vtx][j] - sub[j], dWw[j], dw);
        dw = fmaf(bb[vtx] - sub[8], dWw[8], dw);
        wv4[vtx] = bb[vtx] + dw;
    }
    float acc[20];
    #pragma unroll
    for (int c = 0; c < 20; ++c) acc[c] = clsb[c];
    #pragma unroll
    for (int vtx = 0; vtx < 4; ++vtx) {
        const float* pr = proj + (size_t)ids[vtx] * 20;
        const float wgt = wv4[vtx];
        #pragma unroll
        for (int cq = 0; cq < 5; ++cq) {
            const float4 t = *(const float4*)(pr + cq * 4);
            acc[cq * 4 + 0] = fmaf(wgt, t.x, acc[cq * 4 + 0]);
            acc[cq * 4 + 1] = fmaf(wgt, t.y, acc[cq * 4 + 1]);
            acc[cq * 4 + 2] = fmaf(wgt, t.z, acc[cq * 4 + 2]);
            acc[cq * 4 + 3] = fmaf(wgt, t.w, acc[cq * 4 + 3]);
        }
    }
    float* o = out + (size_t)p * 20;
    #pragma unroll
    for (int cq = 0; cq < 5; ++cq)
        *(float4*)(o + cq * 4) = make_float4(acc[cq * 4 + 0], acc[cq * 4 + 1],
                                             acc[cq * 4 + 2], acc[cq * 4 + 3]);
}

// ---------------------------------------------------------------------------
extern "C" void kernel_launch(void* const* d_in, const int* in_sizes, int n_in,
                              void* d_out, int out_size, void* d_ws, size_t ws_size,
                              hipStream_t stream) {
    const float* lv   = (const float*)d_in[0];
    // d_in[1] = positions — unused by the reference
    const int*   idx  = (const int*)d_in[2];
    const float* bary = (const float*)d_in[3];
    const float* gn0w = (const float*)d_in[4];
    const float* gn0b = (const float*)d_in[5];
    const float* W0   = (const float*)d_in[6];
    const float* gn1w = (const float*)d_in[7];
    const float* gn1b = (const float*)d_in[8];
    const float* W1   = (const float*)d_in[9];
    const float* gn2w = (const float*)d_in[10];
    const float* gn2b = (const float*)d_in[11];
    const float* W2   = (const float*)d_in[12];
    const float* gamma= (const float*)d_in[13];
    const float* beta = (const float*)d_in[14];
    const float* dWw  = (const float*)d_in[15];
    const float* dWb  = (const float*)d_in[16];
    const float* clsW = (const float*)d_in[17];
    const float* clsb = (const float*)d_in[18];
    float* out = (float*)d_out;

    float* w = (float*)d_ws;
    float* stats0 = w;            // 64
    float* stats1 = w + 64;       // 64
    float* stats2 = w + 128;      // 64
    float* A0 = w + 192; float* B0 = w + 256;
    float* A1 = w + 320; float* B1 = w + 384;
    float* A2 = w + 448; float* B2 = w + 480;
    float* proj = w + 512;                       // NV*20 = 6.0M floats
    float* x0 = proj + (size_t)NVV * 20;         // NV*64 = 19.2M floats
    float* x1 = x0 + (size_t)NVV * 64;           // NV*32 = 9.6M floats
    float* x2 = x0;                              // reuse x0 region after K3

    hipMemsetAsync(w, 0, 192 * sizeof(float), stream);
    k_stats0<<<512, 256, 0, stream>>>(lv, stats0);
    k_finalize<<<1, 64, 0, stream>>>(stats0, gn0w, gn0b, A0, B0, 64, 1.f / (NVV * 2.f));
    k_stage0<<<1172, 256, 0, stream>>>(lv, W0, clsW, A0, B0, x0, proj, stats1);
    k_finalize<<<1, 64, 0, stream>>>(stats1, gn1w, gn1b, A1, B1, 64, 1.f / (NVV * 2.f));
    k_stage1<<<1172, 256, 0, stream>>>(x0, W1, A1, B1, x1, stats2);
    k_finalize<<<1, 32, 0, stream>>>(stats2, gn2w, gn2b, A2, B2, 32, 1.f / (float)NVV);
    k_stage2<<<1172, 256, 0, stream>>>(x1, W2, A2, B2, x2);
    k_final<<<1954, 256, 0, stream>>>(idx, bary, x2, proj, gamma, beta, dWw, dWb, clsb, out);
}

// Round 2
// 640.724 us; speedup vs baseline: 7.1551x; 7.1551x over previous
//
#include <hip/hip_runtime.h>

#define NVV 300000
#define PCNT 500000
#define EPSV 1e-5f
#define NREP 8   // replica stat buffers to spread atomic contention

// ---------------------------------------------------------------------------
// K1: global GroupNorm stats over lv [NV,64], 32 groups x 2ch, group-level.
// Per-wave butterfly -> LDS accumulate -> 64 atomics/block into replica.
// ---------------------------------------------------------------------------
__global__ __launch_bounds__(256) void k_stats0(const float* __restrict__ lv,
                                                float* __restrict__ rep) {
    __shared__ float sStat[64];
    const int t = threadIdx.x;
    if (t < 64) sStat[t] = 0.f;
    __syncthreads();
    const int c4 = t & 15;   // float4 index in row (channels 4c4..4c4+3)
    const int sub = t >> 4;  // 16 row streams per block
    float s0 = 0.f, q0 = 0.f, s1 = 0.f, q1 = 0.f;
    for (int r = blockIdx.x * 16 + sub; r < NVV; r += gridDim.x * 16) {
        const float4 v = *(const float4*)(lv + (size_t)r * 64 + c4 * 4);
        s0 += v.x + v.y; q0 += v.x * v.x + v.y * v.y;
        s1 += v.z + v.w; q1 += v.z * v.z + v.w * v.w;
    }
    #pragma unroll
    for (int d = 16; d < 64; d <<= 1) {
        s0 += __shfl_xor(s0, d); q0 += __shfl_xor(q0, d);
        s1 += __shfl_xor(s1, d); q1 += __shfl_xor(q1, d);
    }
    if ((t & 63) < 16) {   // groups g0=2c4, g1=2c4+1; layout [g*2 + {s,q}]
        atomicAdd(&sStat[(c4 * 2) * 2 + 0], s0);
        atomicAdd(&sStat[(c4 * 2) * 2 + 1], q0);
        atomicAdd(&sStat[(c4 * 2 + 1) * 2 + 0], s1);
        atomicAdd(&sStat[(c4 * 2 + 1) * 2 + 1], q1);
    }
    __syncthreads();
    if (t < 64) atomicAdd(&rep[(blockIdx.x & (NREP - 1)) * 64 + t], sStat[t]);
}

// ---------------------------------------------------------------------------
// Finalize: sum replicas, group stats -> per-channel affine A (scale), B
// (shift) so apply kernels do xn = relu(v*A + B).
// ---------------------------------------------------------------------------
__global__ void k_finalize(const float* __restrict__ rep,
                           const float* __restrict__ gw,
                           const float* __restrict__ gb,
                           float* __restrict__ A, float* __restrict__ B,
                           int C, float cntInv) {
    const int k = threadIdx.x;
    if (k >= C) return;
    const int g = (C == 32) ? k : (k >> 1);
    float s = 0.f, q = 0.f;
    #pragma unroll
    for (int r = 0; r < NREP; ++r) { s += rep[r * 64 + g * 2]; q += rep[r * 64 + g * 2 + 1]; }
    const float mean = s * cntInv;
    const float var = q * cntInv - mean * mean;
    const float rs = rsqrtf(var + EPSV);
    const float a = rs * gw[k];
    A[k] = a;
    B[k] = gb[k] - mean * a;
}

// ---------------------------------------------------------------------------
// K2: stage0.  lane = row, 64 rows/wave, 256 rows/block.  Weights in LDS.
//   proj = raw lv @ clsW^T  [NV,20];  x0 = relu(GN0(lv)) @ W0^T  [NV,64]
//   fused group-level stats for GN1 (butterfly -> LDS -> replica atomics)
// ---------------------------------------------------------------------------
__global__ __launch_bounds__(256, 3) void k_stage0(const float* __restrict__ lv,
        const float* __restrict__ W0, const float* __restrict__ clsW,
        const float* __restrict__ A, const float* __restrict__ B,
        float* __restrict__ x0, float* __restrict__ proj,
        float* __restrict__ rep1) {
    __shared__ float sW[64 * 64];
    __shared__ float sC[20 * 64];
    __shared__ float sAB[128];
    __shared__ float sStat[64];
    const int t = threadIdx.x;
    for (int i = t; i < 64 * 64 / 4; i += 256) ((float4*)sW)[i] = ((const float4*)W0)[i];
    for (int i = t; i < 20 * 64 / 4; i += 256) ((float4*)sC)[i] = ((const float4*)clsW)[i];
    if (t < 64) { sAB[t] = A[t]; sAB[64 + t] = B[t]; sStat[t] = 0.f; }
    __syncthreads();

    const int lane = t & 63;
    const int row = (blockIdx.x * 4 + (t >> 6)) * 64 + lane;
    const bool valid = row < NVV;
    const int r = valid ? row : NVV - 1;
    const float* src = lv + (size_t)r * 64;
    float v[64];
    #pragma unroll
    for (int k4 = 0; k4 < 16; ++k4) {
        const float4 u = *(const float4*)(src + k4 * 4);
        v[4 * k4 + 0] = u.x; v[4 * k4 + 1] = u.y; v[4 * k4 + 2] = u.z; v[4 * k4 + 3] = u.w;
    }
    // ---- proj on RAW lv ----
    #pragma unroll
    for (int cq = 0; cq < 5; ++cq) {
        float a0 = 0.f, a1 = 0.f, a2 = 0.f, a3 = 0.f;
        #pragma unroll
        for (int k4 = 0; k4 < 16; ++k4) {
            const float4 w0 = *(const float4*)&sC[(cq * 4 + 0) * 64 + k4 * 4];
            const float4 w1 = *(const float4*)&sC[(cq * 4 + 1) * 64 + k4 * 4];
            const float4 w2 = *(const float4*)&sC[(cq * 4 + 2) * 64 + k4 * 4];
            const float4 w3 = *(const float4*)&sC[(cq * 4 + 3) * 64 + k4 * 4];
            const float v0 = v[4 * k4], v1 = v[4 * k4 + 1], v2 = v[4 * k4 + 2], v3 = v[4 * k4 + 3];
            a0 = fmaf(v0, w0.x, fmaf(v1, w0.y, fmaf(v2, w0.z, fmaf(v3, w0.w, a0))));
            a1 = fmaf(v0, w1.x, fmaf(v1, w1.y, fmaf(v2, w1.z, fmaf(v3, w1.w, a1))));
            a2 = fmaf(v0, w2.x, fmaf(v1, w2.y, fmaf(v2, w2.z, fmaf(v3, w2.w, a2))));
            a3 = fmaf(v0, w3.x, fmaf(v1, w3.y, fmaf(v2, w3.z, fmaf(v3, w3.w, a3))));
        }
        if (valid) *(float4*)(proj + (size_t)row * 20 + cq * 4) = make_float4(a0, a1, a2, a3);
    }
    // ---- normalize + relu ----
    #pragma unroll
    for (int k4 = 0; k4 < 16; ++k4) {
        const float4 a4 = *(const float4*)&sAB[k4 * 4];
        const float4 b4 = *(const float4*)&sAB[64 + k4 * 4];
        v[4 * k4 + 0] = fmaxf(fmaf(v[4 * k4 + 0], a4.x, b4.x), 0.f);
        v[4 * k4 + 1] = fmaxf(fmaf(v[4 * k4 + 1], a4.y, b4.y), 0.f);
        v[4 * k4 + 2] = fmaxf(fmaf(v[4 * k4 + 2], a4.z, b4.z), 0.f);
        v[4 * k4 + 3] = fmaxf(fmaf(v[4 * k4 + 3], a4.w, b4.w), 0.f);
    }
    // ---- x0 = xn @ W0^T + fused stats (groups 2jq: ch a0,a1 / 2jq+1: a2,a3) ----
    #pragma unroll
    for (int jq = 0; jq < 16; ++jq) {
        float a0 = 0.f, a1 = 0.f, a2 = 0.f, a3 = 0.f;
        #pragma unroll
        for (int k4 = 0; k4 < 16; ++k4) {
            const float4 w0 = *(const float4*)&sW[(jq * 4 + 0) * 64 + k4 * 4];
            const float4 w1 = *(const float4*)&sW[(jq * 4 + 1) * 64 + k4 * 4];
            const float4 w2 = *(const float4*)&sW[(jq * 4 + 2) * 64 + k4 * 4];
            const float4 w3 = *(const float4*)&sW[(jq * 4 + 3) * 64 + k4 * 4];
            const float v0 = v[4 * k4], v1 = v[4 * k4 + 1], v2 = v[4 * k4 + 2], v3 = v[4 * k4 + 3];
            a0 = fmaf(v0, w0.x, fmaf(v1, w0.y, fmaf(v2, w0.z, fmaf(v3, w0.w, a0))));
            a1 = fmaf(v0, w1.x, fmaf(v1, w1.y, fmaf(v2, w1.z, fmaf(v3, w1.w, a1))));
            a2 = fmaf(v0, w2.x, fmaf(v1, w2.y, fmaf(v2, w2.z, fmaf(v3, w2.w, a2))));
            a3 = fmaf(v0, w3.x, fmaf(v1, w3.y, fmaf(v2, w3.z, fmaf(v3, w3.w, a3))));
        }
        if (valid) *(float4*)(x0 + (size_t)row * 64 + jq * 4) = make_float4(a0, a1, a2, a3);
        float sA = valid ? a0 + a1 : 0.f;
        float qA = valid ? a0 * a0 + a1 * a1 : 0.f;
        float sB = valid ? a2 + a3 : 0.f;
        float qB = valid ? a2 * a2 + a3 * a3 : 0.f;
        #pragma unroll
        for (int d = 1; d < 64; d <<= 1) {
            sA += __shfl_xor(sA, d); qA += __shfl_xor(qA, d);
            sB += __shfl_xor(sB, d); qB += __shfl_xor(qB, d);
        }
        if (lane == 0) {
            atomicAdd(&sStat[(2 * jq) * 2 + 0], sA);
            atomicAdd(&sStat[(2 * jq) * 2 + 1], qA);
            atomicAdd(&sStat[(2 * jq + 1) * 2 + 0], sB);
            atomicAdd(&sStat[(2 * jq + 1) * 2 + 1], qB);
        }
    }
    __syncthreads();
    if (t < 64) atomicAdd(&rep1[(blockIdx.x & (NREP - 1)) * 64 + t], sStat[t]);
}

// ---------------------------------------------------------------------------
// K3: stage1.  x1 = relu(GN1(x0)) @ W1^T [NV,32]; fused stats (1 ch/group).
// ---------------------------------------------------------------------------
__global__ __launch_bounds__(256, 3) void k_stage1(const float* __restrict__ x0,
        const float* __restrict__ W1,
        const float* __restrict__ A, const float* __restrict__ B,
        float* __restrict__ x1, float* __restrict__ rep2) {
    __shared__ float sW[32 * 64];
    __shared__ float sAB[128];
    __shared__ float sStat[64];
    const int t = threadIdx.x;
    for (int i = t; i < 32 * 64 / 4; i += 256) ((float4*)sW)[i] = ((const float4*)W1)[i];
    if (t < 64) { sAB[t] = A[t]; sAB[64 + t] = B[t]; sStat[t] = 0.f; }
    __syncthreads();

    const int lane = t & 63;
    const int row = (blockIdx.x * 4 + (t >> 6)) * 64 + lane;
    const bool valid = row < NVV;
    const int r = valid ? row : NVV - 1;
    const float* src = x0 + (size_t)r * 64;
    float v[64];
    #pragma unroll
    for (int k4 = 0; k4 < 16; ++k4) {
        const float4 u = *(const float4*)(src + k4 * 4);
        const float4 a4 = *(const float4*)&sAB[k4 * 4];
        const float4 b4 = *(const float4*)&sAB[64 + k4 * 4];
        v[4 * k4 + 0] = fmaxf(fmaf(u.x, a4.x, b4.x), 0.f);
        v[4 * k4 + 1] = fmaxf(fmaf(u.y, a4.y, b4.y), 0.f);
        v[4 * k4 + 2] = fmaxf(fmaf(u.z, a4.z, b4.z), 0.f);
        v[4 * k4 + 3] = fmaxf(fmaf(u.w, a4.w, b4.w), 0.f);
    }
    #pragma unroll
    for (int jq = 0; jq < 8; ++jq) {
        float a0 = 0.f, a1 = 0.f, a2 = 0.f, a3 = 0.f;
        #pragma unroll
        for (int k4 = 0; k4 < 16; ++k4) {
            const float4 w0 = *(const float4*)&sW[(jq * 4 + 0) * 64 + k4 * 4];
            const float4 w1 = *(const float4*)&sW[(jq * 4 + 1) * 64 + k4 * 4];
            const float4 w2 = *(const float4*)&sW[(jq * 4 + 2) * 64 + k4 * 4];
            const float4 w3 = *(const float4*)&sW[(jq * 4 + 3) * 64 + k4 * 4];
            const float v0 = v[4 * k4], v1 = v[4 * k4 + 1], v2 = v[4 * k4 + 2], v3 = v[4 * k4 + 3];
            a0 = fmaf(v0, w0.x, fmaf(v1, w0.y, fmaf(v2, w0.z, fmaf(v3, w0.w, a0))));
            a1 = fmaf(v0, w1.x, fmaf(v1, w1.y, fmaf(v2, w1.z, fmaf(v3, w1.w, a1))));
            a2 = fmaf(v0, w2.x, fmaf(v1, w2.y, fmaf(v2, w2.z, fmaf(v3, w2.w, a2))));
            a3 = fmaf(v0, w3.x, fmaf(v1, w3.y, fmaf(v2, w3.z, fmaf(v3, w3.w, a3))));
        }
        if (valid) *(float4*)(x1 + (size_t)row * 32 + jq * 4) = make_float4(a0, a1, a2, a3);
        float s0 = valid ? a0 : 0.f, q0 = valid ? a0 * a0 : 0.f;
        float s1 = valid ? a1 : 0.f, q1 = valid ? a1 * a1 : 0.f;
        float s2 = valid ? a2 : 0.f, q2 = valid ? a2 * a2 : 0.f;
        float s3 = valid ? a3 : 0.f, q3 = valid ? a3 * a3 : 0.f;
        #pragma unroll
        for (int d = 1; d < 64; d <<= 1) {
            s0 += __shfl_xor(s0, d); q0 += __shfl_xor(q0, d);
            s1 += __shfl_xor(s1, d); q1 += __shfl_xor(q1, d);
            s2 += __shfl_xor(s2, d); q2 += __shfl_xor(q2, d);
            s3 += __shfl_xor(s3, d); q3 += __shfl_xor(q3, d);
        }
        if (lane == 0) {
            atomicAdd(&sStat[(jq * 4 + 0) * 2 + 0], s0); atomicAdd(&sStat[(jq * 4 + 0) * 2 + 1], q0);
            atomicAdd(&sStat[(jq * 4 + 1) * 2 + 0], s1); atomicAdd(&sStat[(jq * 4 + 1) * 2 + 1], q1);
            atomicAdd(&sStat[(jq * 4 + 2) * 2 + 0], s2); atomicAdd(&sStat[(jq * 4 + 2) * 2 + 1], q2);
            atomicAdd(&sStat[(jq * 4 + 3) * 2 + 0], s3); atomicAdd(&sStat[(jq * 4 + 3) * 2 + 1], q3);
        }
    }
    __syncthreads();
    if (t < 64) atomicAdd(&rep2[(blockIdx.x & (NREP - 1)) * 64 + t], sStat[t]);
}

// ---------------------------------------------------------------------------
// K4: stage2 (bottleneck).  x2 = relu(GN2(x1)) @ W2^T  [NV,8].
// ---------------------------------------------------------------------------
__global__ __launch_bounds__(256, 4) void k_stage2(const float* __restrict__ x1,
        const float* __restrict__ W2,
        const float* __restrict__ A, const float* __restrict__ B,
        float* __restrict__ x2) {
    __shared__ float sW[8 * 32];
    __shared__ float sAB[64];
    const int t = threadIdx.x;
    if (t < 64) ((float4*)sW)[t] = ((const float4*)W2)[t];
    if (t < 32) { sAB[t] = A[t]; sAB[32 + t] = B[t]; }
    __syncthreads();

    const int row = (blockIdx.x * 4 + (t >> 6)) * 64 + (t & 63);
    const bool valid = row < NVV;
    const int r = valid ? row : NVV - 1;
    const float* src = x1 + (size_t)r * 32;
    float v[32];
    #pragma unroll
    for (int k4 = 0; k4 < 8; ++k4) {
        const float4 u = *(const float4*)(src + k4 * 4);
        const float4 a4 = *(const float4*)&sAB[k4 * 4];
        const float4 b4 = *(const float4*)&sAB[32 + k4 * 4];
        v[4 * k4 + 0] = fmaxf(fmaf(u.x, a4.x, b4.x), 0.f);
        v[4 * k4 + 1] = fmaxf(fmaf(u.y, a4.y, b4.y), 0.f);
        v[4 * k4 + 2] = fmaxf(fmaf(u.z, a4.z, b4.z), 0.f);
        v[4 * k4 + 3] = fmaxf(fmaf(u.w, a4.w, b4.w), 0.f);
    }
    #pragma unroll
    for (int jq = 0; jq < 2; ++jq) {
        float a0 = 0.f, a1 = 0.f, a2 = 0.f, a3 = 0.f;
        #pragma unroll
        for (int k4 = 0; k4 < 8; ++k4) {
            const float4 w0 = *(const float4*)&sW[(jq * 4 + 0) * 32 + k4 * 4];
            const float4 w1 = *(const float4*)&sW[(jq * 4 + 1) * 32 + k4 * 4];
            const float4 w2 = *(const float4*)&sW[(jq * 4 + 2) * 32 + k4 * 4];
            const float4 w3 = *(const float4*)&sW[(jq * 4 + 3) * 32 + k4 * 4];
            const float v0 = v[4 * k4], v1 = v[4 * k4 + 1], v2 = v[4 * k4 + 2], v3 = v[4 * k4 + 3];
            a0 = fmaf(v0, w0.x, fmaf(v1, w0.y, fmaf(v2, w0.z, fmaf(v3, w0.w, a0))));
            a1 = fmaf(v0, w1.x, fmaf(v1, w1.y, fmaf(v2, w1.z, fmaf(v3, w1.w, a1))));
            a2 = fmaf(v0, w2.x, fmaf(v1, w2.y, fmaf(v2, w2.z, fmaf(v3, w2.w, a2))));
            a3 = fmaf(v0, w3.x, fmaf(v1, w3.y, fmaf(v2, w3.z, fmaf(v3, w3.w, a3))));
        }
        if (valid) *(float4*)(x2 + (size_t)row * 8 + jq * 4) = make_float4(a0, a1, a2, a3);
    }
}

// ---------------------------------------------------------------------------
// K5: per-position gather + max-normalize + delta weights + classify via proj.
// out[p,c] = cls_b[c] + sum_v (bary_v + dw_v) * proj[idx_v, c]
// ---------------------------------------------------------------------------
__global__ __launch_bounds__(256, 4) void k_final(const int* __restrict__ idx,
        const float* __restrict__ bary, const float* __restrict__ x2,
        const float* __restrict__ proj, const float* __restrict__ gamma,
        const float* __restrict__ beta, const float* __restrict__ dWw,
        const float* __restrict__ dWb, const float* __restrict__ clsb,
        float* __restrict__ out) {
    const int p = blockIdx.x * 256 + threadIdx.x;
    if (p >= PCNT) return;
    const int4 iv = *(const int4*)(idx + (size_t)p * 4);
    const float4 bv = *(const float4*)(bary + (size_t)p * 4);
    const int ids[4] = {iv.x, iv.y, iv.z, iv.w};
    const float bb[4] = {bv.x, bv.y, bv.z, bv.w};
    float g[4][8];
    #pragma unroll
    for (int vtx = 0; vtx < 4; ++vtx) {
        const float* s = x2 + (size_t)ids[vtx] * 8;
        const float4 u0 = *(const float4*)(s);
        const float4 u1 = *(const float4*)(s + 4);
        g[vtx][0] = u0.x; g[vtx][1] = u0.y; g[vtx][2] = u0.z; g[vtx][3] = u0.w;
        g[vtx][4] = u1.x; g[vtx][5] = u1.y; g[vtx][6] = u1.z; g[vtx][7] = u1.w;
    }
    float sub[9];
    #pragma unroll
    for (int j = 0; j < 8; ++j) {
        const float mx = fmaxf(fmaxf(g[0][j], g[1][j]), fmaxf(g[2][j], g[3][j]));
        sub[j] = fmaf(gamma[j], mx, beta[j]);
    }
    {
        const float mx8 = fmaxf(fmaxf(bb[0], bb[1]), fmaxf(bb[2], bb[3]));
        sub[8] = fmaf(gamma[8], mx8, beta[8]);
    }
    float wv4[4];
    #pragma unroll
    for (int vtx = 0; vtx < 4; ++vtx) {
        float dw = dWb[0];
        #pragma unroll
        for (int j = 0; j < 8; ++j) dw = fmaf(g[vtx][j] - sub[j], dWw[j], dw);
        dw = fmaf(bb[vtx] - sub[8], dWw[8], dw);
        wv4[vtx] = bb[vtx] + dw;
    }
    float acc[20];
    #pragma unroll
    for (int c = 0; c < 20; ++c) acc[c] = clsb[c];
    #pragma unroll
    for (int vtx = 0; vtx < 4; ++vtx) {
        const float* pr = proj + (size_t)ids[vtx] * 20;
        const float wgt = wv4[vtx];
        #pragma unroll
        for (int cq = 0; cq < 5; ++cq) {
            const float4 u = *(const float4*)(pr + cq * 4);
            acc[cq * 4 + 0] = fmaf(wgt, u.x, acc[cq * 4 + 0]);
            acc[cq * 4 + 1] = fmaf(wgt, u.y, acc[cq * 4 + 1]);
            acc[cq * 4 + 2] = fmaf(wgt, u.z, acc[cq * 4 + 2]);
            acc[cq * 4 + 3] = fmaf(wgt, u.w, acc[cq * 4 + 3]);
        }
    }
    float* o = out + (size_t)p * 20;
    #pragma unroll
    for (int cq = 0; cq < 5; ++cq)
        *(float4*)(o + cq * 4) = make_float4(acc[cq * 4 + 0], acc[cq * 4 + 1],
                                             acc[cq * 4 + 2], acc[cq * 4 + 3]);
}

// ---------------------------------------------------------------------------
extern "C" void kernel_launch(void* const* d_in, const int* in_sizes, int n_in,
                              void* d_out, int out_size, void* d_ws, size_t ws_size,
                              hipStream_t stream) {
    const float* lv   = (const float*)d_in[0];
    // d_in[1] = positions — unused by the reference
    const int*   idx  = (const int*)d_in[2];
    const float* bary = (const float*)d_in[3];
    const float* gn0w = (const float*)d_in[4];
    const float* gn0b = (const float*)d_in[5];
    const float* W0   = (const float*)d_in[6];
    const float* gn1w = (const float*)d_in[7];
    const float* gn1b = (const float*)d_in[8];
    const float* W1   = (const float*)d_in[9];
    const float* gn2w = (const float*)d_in[10];
    const float* gn2b = (const float*)d_in[11];
    const float* W2   = (const float*)d_in[12];
    const float* gamma= (const float*)d_in[13];
    const float* beta = (const float*)d_in[14];
    const float* dWw  = (const float*)d_in[15];
    const float* dWb  = (const float*)d_in[16];
    const float* clsW = (const float*)d_in[17];
    const float* clsb = (const float*)d_in[18];
    float* out = (float*)d_out;

    float* w = (float*)d_ws;
    float* rep0 = w;                  // 8*64
    float* rep1 = w + 512;            // 8*64
    float* rep2 = w + 1024;           // 8*64
    float* A0 = w + 1536; float* B0 = w + 1600;
    float* A1 = w + 1664; float* B1 = w + 1728;
    float* A2 = w + 1792; float* B2 = w + 1856;
    float* proj = w + 2048;                      // NV*20
    float* x0 = proj + (size_t)NVV * 20;         // NV*64
    float* x1 = x0 + (size_t)NVV * 64;           // NV*32
    float* x2 = x0;                              // reuse x0 region after K3

    hipMemsetAsync(w, 0, 1536 * sizeof(float), stream);
    k_stats0<<<512, 256, 0, stream>>>(lv, rep0);
    k_finalize<<<1, 64, 0, stream>>>(rep0, gn0w, gn0b, A0, B0, 64, 1.f / (NVV * 2.f));
    k_stage0<<<1172, 256, 0, stream>>>(lv, W0, clsW, A0, B0, x0, proj, rep1);
    k_finalize<<<1, 64, 0, stream>>>(rep1, gn1w, gn1b, A1, B1, 64, 1.f / (NVV * 2.f));
    k_stage1<<<1172, 256, 0, stream>>>(x0, W1, A1, B1, x1, rep2);
    k_finalize<<<1, 32, 0, stream>>>(rep2, gn2w, gn2b, A2, B2, 32, 1.f / (float)NVV);
    k_stage2<<<1172, 256, 0, stream>>>(x1, W2, A2, B2, x2);
    k_final<<<1954, 256, 0, stream>>>(idx, bary, x2, proj, gamma, beta, dWw, dWb, clsb, out);
}

// Round 3
// 510.052 us; speedup vs baseline: 8.9882x; 1.2562x over previous
//
#include <hip/hip_runtime.h>

#define NVV 300000
#define PCNT 500000
#define EPSV 1e-5f
#define NREP 8   // replica stat buffers to spread atomic contention

// Intermediate layouts:
//   x0q : float4[16][NVV]  plane layout — plane jq holds cols 4jq..4jq+3 of x0
//   x1q : float4[8][NVV]   plane layout for x1 (32 cols)
//   proj: float [NVV][20]  row-major (k_final gathers 80B rows)
//   x2  : float [NVV][8]   row-major (k_final gathers 32B rows)

// ---------------------------------------------------------------------------
// K1: global GroupNorm stats over lv [NV,64], 32 groups x 2ch.
// ---------------------------------------------------------------------------
__global__ __launch_bounds__(256) void k_stats0(const float* __restrict__ lv,
                                                float* __restrict__ rep) {
    __shared__ float sStat[64];
    const int t = threadIdx.x;
    if (t < 64) sStat[t] = 0.f;
    __syncthreads();
    const int c4 = t & 15;
    const int sub = t >> 4;
    float s0 = 0.f, q0 = 0.f, s1 = 0.f, q1 = 0.f;
    for (int r = blockIdx.x * 16 + sub; r < NVV; r += gridDim.x * 16) {
        const float4 v = *(const float4*)(lv + (size_t)r * 64 + c4 * 4);
        s0 += v.x + v.y; q0 += v.x * v.x + v.y * v.y;
        s1 += v.z + v.w; q1 += v.z * v.z + v.w * v.w;
    }
    #pragma unroll
    for (int d = 16; d < 64; d <<= 1) {
        s0 += __shfl_xor(s0, d); q0 += __shfl_xor(q0, d);
        s1 += __shfl_xor(s1, d); q1 += __shfl_xor(q1, d);
    }
    if ((t & 63) < 16) {
        atomicAdd(&sStat[(c4 * 2) * 2 + 0], s0);
        atomicAdd(&sStat[(c4 * 2) * 2 + 1], q0);
        atomicAdd(&sStat[(c4 * 2 + 1) * 2 + 0], s1);
        atomicAdd(&sStat[(c4 * 2 + 1) * 2 + 1], q1);
    }
    __syncthreads();
    if (t < 64) atomicAdd(&rep[(blockIdx.x & (NREP - 1)) * 64 + t], sStat[t]);
}

// ---------------------------------------------------------------------------
// Finalize: sum replicas -> per-channel affine A (scale), B (shift).
// ---------------------------------------------------------------------------
__global__ void k_finalize(const float* __restrict__ rep,
                           const float* __restrict__ gw,
                           const float* __restrict__ gb,
                           float* __restrict__ A, float* __restrict__ B,
                           int C, float cntInv) {
    const int k = threadIdx.x;
    if (k >= C) return;
    const int g = (C == 32) ? k : (k >> 1);
    float s = 0.f, q = 0.f;
    #pragma unroll
    for (int r = 0; r < NREP; ++r) { s += rep[r * 64 + g * 2]; q += rep[r * 64 + g * 2 + 1]; }
    const float mean = s * cntInv;
    const float var = q * cntInv - mean * mean;
    const float rs = rsqrtf(var + EPSV);
    const float a = rs * gw[k];
    A[k] = a;
    B[k] = gb[k] - mean * a;
}

// ---------------------------------------------------------------------------
// K2: stage0.  lane = row.  proj -> LDS -> coalesced flush; x0 -> planes.
// ---------------------------------------------------------------------------
__global__ __launch_bounds__(256, 3) void k_stage0(const float* __restrict__ lv,
        const float* __restrict__ W0, const float* __restrict__ clsW,
        const float* __restrict__ A, const float* __restrict__ B,
        float4* __restrict__ x0q, float* __restrict__ proj,
        float* __restrict__ rep1) {
    __shared__ float sW[64 * 64];
    __shared__ float sC[20 * 64];
    __shared__ float sAB[128];
    __shared__ float sStat[64];
    __shared__ float sProj[256 * 20];
    const int t = threadIdx.x;
    for (int i = t; i < 64 * 64 / 4; i += 256) ((float4*)sW)[i] = ((const float4*)W0)[i];
    for (int i = t; i < 20 * 64 / 4; i += 256) ((float4*)sC)[i] = ((const float4*)clsW)[i];
    if (t < 64) { sAB[t] = A[t]; sAB[64 + t] = B[t]; sStat[t] = 0.f; }
    __syncthreads();

    const int lane = t & 63;
    const int blockRow0 = blockIdx.x * 256;
    const int row = blockRow0 + t;
    const bool valid = row < NVV;
    const int r = valid ? row : NVV - 1;
    const float* src = lv + (size_t)r * 64;
    float v[64];
    #pragma unroll
    for (int k4 = 0; k4 < 16; ++k4) {
        const float4 u = *(const float4*)(src + k4 * 4);
        v[4 * k4 + 0] = u.x; v[4 * k4 + 1] = u.y; v[4 * k4 + 2] = u.z; v[4 * k4 + 3] = u.w;
    }
    // ---- proj on RAW lv -> LDS ----
    #pragma unroll
    for (int cq = 0; cq < 5; ++cq) {
        float a0 = 0.f, a1 = 0.f, a2 = 0.f, a3 = 0.f;
        #pragma unroll
        for (int k4 = 0; k4 < 16; ++k4) {
            const float4 w0 = *(const float4*)&sC[(cq * 4 + 0) * 64 + k4 * 4];
            const float4 w1 = *(const float4*)&sC[(cq * 4 + 1) * 64 + k4 * 4];
            const float4 w2 = *(const float4*)&sC[(cq * 4 + 2) * 64 + k4 * 4];
            const float4 w3 = *(const float4*)&sC[(cq * 4 + 3) * 64 + k4 * 4];
            const float v0 = v[4 * k4], v1 = v[4 * k4 + 1], v2 = v[4 * k4 + 2], v3 = v[4 * k4 + 3];
            a0 = fmaf(v0, w0.x, fmaf(v1, w0.y, fmaf(v2, w0.z, fmaf(v3, w0.w, a0))));
            a1 = fmaf(v0, w1.x, fmaf(v1, w1.y, fmaf(v2, w1.z, fmaf(v3, w1.w, a1))));
            a2 = fmaf(v0, w2.x, fmaf(v1, w2.y, fmaf(v2, w2.z, fmaf(v3, w2.w, a2))));
            a3 = fmaf(v0, w3.x, fmaf(v1, w3.y, fmaf(v2, w3.z, fmaf(v3, w3.w, a3))));
        }
        *(float4*)&sProj[t * 20 + cq * 4] = make_float4(a0, a1, a2, a3);
    }
    // ---- normalize + relu ----
    #pragma unroll
    for (int k4 = 0; k4 < 16; ++k4) {
        const float4 a4 = *(const float4*)&sAB[k4 * 4];
        const float4 b4 = *(const float4*)&sAB[64 + k4 * 4];
        v[4 * k4 + 0] = fmaxf(fmaf(v[4 * k4 + 0], a4.x, b4.x), 0.f);
        v[4 * k4 + 1] = fmaxf(fmaf(v[4 * k4 + 1], a4.y, b4.y), 0.f);
        v[4 * k4 + 2] = fmaxf(fmaf(v[4 * k4 + 2], a4.z, b4.z), 0.f);
        v[4 * k4 + 3] = fmaxf(fmaf(v[4 * k4 + 3], a4.w, b4.w), 0.f);
    }
    // ---- x0 = xn @ W0^T -> plane layout; fused stats ----
    #pragma unroll
    for (int jq = 0; jq < 16; ++jq) {
        float a0 = 0.f, a1 = 0.f, a2 = 0.f, a3 = 0.f;
        #pragma unroll
        for (int k4 = 0; k4 < 16; ++k4) {
            const float4 w0 = *(const float4*)&sW[(jq * 4 + 0) * 64 + k4 * 4];
            const float4 w1 = *(const float4*)&sW[(jq * 4 + 1) * 64 + k4 * 4];
            const float4 w2 = *(const float4*)&sW[(jq * 4 + 2) * 64 + k4 * 4];
            const float4 w3 = *(const float4*)&sW[(jq * 4 + 3) * 64 + k4 * 4];
            const float v0 = v[4 * k4], v1 = v[4 * k4 + 1], v2 = v[4 * k4 + 2], v3 = v[4 * k4 + 3];
            a0 = fmaf(v0, w0.x, fmaf(v1, w0.y, fmaf(v2, w0.z, fmaf(v3, w0.w, a0))));
            a1 = fmaf(v0, w1.x, fmaf(v1, w1.y, fmaf(v2, w1.z, fmaf(v3, w1.w, a1))));
            a2 = fmaf(v0, w2.x, fmaf(v1, w2.y, fmaf(v2, w2.z, fmaf(v3, w2.w, a2))));
            a3 = fmaf(v0, w3.x, fmaf(v1, w3.y, fmaf(v2, w3.z, fmaf(v3, w3.w, a3))));
        }
        if (valid) x0q[(size_t)jq * NVV + row] = make_float4(a0, a1, a2, a3);
        float sA = valid ? a0 + a1 : 0.f;
        float qA = valid ? a0 * a0 + a1 * a1 : 0.f;
        float sB = valid ? a2 + a3 : 0.f;
        float qB = valid ? a2 * a2 + a3 * a3 : 0.f;
        #pragma unroll
        for (int d = 1; d < 64; d <<= 1) {
            sA += __shfl_xor(sA, d); qA += __shfl_xor(qA, d);
            sB += __shfl_xor(sB, d); qB += __shfl_xor(qB, d);
        }
        if (lane == 0) {
            atomicAdd(&sStat[(2 * jq) * 2 + 0], sA);
            atomicAdd(&sStat[(2 * jq) * 2 + 1], qA);
            atomicAdd(&sStat[(2 * jq + 1) * 2 + 0], sB);
            atomicAdd(&sStat[(2 * jq + 1) * 2 + 1], qB);
        }
    }
    __syncthreads();
    // coalesced proj flush (only valid rows)
    {
        const int validRows = min(256, NVV - blockRow0);
        const int n4 = validRows * 20 / 4;
        const float4* sp = (const float4*)sProj;
        float4* gp = (float4*)(proj + (size_t)blockRow0 * 20);
        for (int i = t; i < n4; i += 256) gp[i] = sp[i];
    }
    if (t < 64) atomicAdd(&rep1[(blockIdx.x & (NREP - 1)) * 64 + t], sStat[t]);
}

// ---------------------------------------------------------------------------
// K3: stage1.  Reads x0 planes, writes x1 planes; fused stats (1 ch/group).
// ---------------------------------------------------------------------------
__global__ __launch_bounds__(256, 3) void k_stage1(const float4* __restrict__ x0q,
        const float* __restrict__ W1,
        const float* __restrict__ A, const float* __restrict__ B,
        float4* __restrict__ x1q, float* __restrict__ rep2) {
    __shared__ float sW[32 * 64];
    __shared__ float sAB[128];
    __shared__ float sStat[64];
    const int t = threadIdx.x;
    for (int i = t; i < 32 * 64 / 4; i += 256) ((float4*)sW)[i] = ((const float4*)W1)[i];
    if (t < 64) { sAB[t] = A[t]; sAB[64 + t] = B[t]; sStat[t] = 0.f; }
    __syncthreads();

    const int lane = t & 63;
    const int row = blockIdx.x * 256 + t;
    const bool valid = row < NVV;
    const int r = valid ? row : NVV - 1;
    float v[64];
    #pragma unroll
    for (int k4 = 0; k4 < 16; ++k4) {
        const float4 u = x0q[(size_t)k4 * NVV + r];
        const float4 a4 = *(const float4*)&sAB[k4 * 4];
        const float4 b4 = *(const float4*)&sAB[64 + k4 * 4];
        v[4 * k4 + 0] = fmaxf(fmaf(u.x, a4.x, b4.x), 0.f);
        v[4 * k4 + 1] = fmaxf(fmaf(u.y, a4.y, b4.y), 0.f);
        v[4 * k4 + 2] = fmaxf(fmaf(u.z, a4.z, b4.z), 0.f);
        v[4 * k4 + 3] = fmaxf(fmaf(u.w, a4.w, b4.w), 0.f);
    }
    #pragma unroll
    for (int jq = 0; jq < 8; ++jq) {
        float a0 = 0.f, a1 = 0.f, a2 = 0.f, a3 = 0.f;
        #pragma unroll
        for (int k4 = 0; k4 < 16; ++k4) {
            const float4 w0 = *(const float4*)&sW[(jq * 4 + 0) * 64 + k4 * 4];
            const float4 w1 = *(const float4*)&sW[(jq * 4 + 1) * 64 + k4 * 4];
            const float4 w2 = *(const float4*)&sW[(jq * 4 + 2) * 64 + k4 * 4];
            const float4 w3 = *(const float4*)&sW[(jq * 4 + 3) * 64 + k4 * 4];
            const float v0 = v[4 * k4], v1 = v[4 * k4 + 1], v2 = v[4 * k4 + 2], v3 = v[4 * k4 + 3];
            a0 = fmaf(v0, w0.x, fmaf(v1, w0.y, fmaf(v2, w0.z, fmaf(v3, w0.w, a0))));
            a1 = fmaf(v0, w1.x, fmaf(v1, w1.y, fmaf(v2, w1.z, fmaf(v3, w1.w, a1))));
            a2 = fmaf(v0, w2.x, fmaf(v1, w2.y, fmaf(v2, w2.z, fmaf(v3, w2.w, a2))));
            a3 = fmaf(v0, w3.x, fmaf(v1, w3.y, fmaf(v2, w3.z, fmaf(v3, w3.w, a3))));
        }
        if (valid) x1q[(size_t)jq * NVV + row] = make_float4(a0, a1, a2, a3);
        float s0 = valid ? a0 : 0.f, q0 = valid ? a0 * a0 : 0.f;
        float s1 = valid ? a1 : 0.f, q1 = valid ? a1 * a1 : 0.f;
        float s2 = valid ? a2 : 0.f, q2 = valid ? a2 * a2 : 0.f;
        float s3 = valid ? a3 : 0.f, q3 = valid ? a3 * a3 : 0.f;
        #pragma unroll
        for (int d = 1; d < 64; d <<= 1) {
            s0 += __shfl_xor(s0, d); q0 += __shfl_xor(q0, d);
            s1 += __shfl_xor(s1, d); q1 += __shfl_xor(q1, d);
            s2 += __shfl_xor(s2, d); q2 += __shfl_xor(q2, d);
            s3 += __shfl_xor(s3, d); q3 += __shfl_xor(q3, d);
        }
        if (lane == 0) {
            atomicAdd(&sStat[(jq * 4 + 0) * 2 + 0], s0); atomicAdd(&sStat[(jq * 4 + 0) * 2 + 1], q0);
            atomicAdd(&sStat[(jq * 4 + 1) * 2 + 0], s1); atomicAdd(&sStat[(jq * 4 + 1) * 2 + 1], q1);
            atomicAdd(&sStat[(jq * 4 + 2) * 2 + 0], s2); atomicAdd(&sStat[(jq * 4 + 2) * 2 + 1], q2);
            atomicAdd(&sStat[(jq * 4 + 3) * 2 + 0], s3); atomicAdd(&sStat[(jq * 4 + 3) * 2 + 1], q3);
        }
    }
    __syncthreads();
    if (t < 64) atomicAdd(&rep2[(blockIdx.x & (NREP - 1)) * 64 + t], sStat[t]);
}

// ---------------------------------------------------------------------------
// K4: stage2.  Reads x1 planes, writes x2 row-major [NV,8].
// ---------------------------------------------------------------------------
__global__ __launch_bounds__(256, 4) void k_stage2(const float4* __restrict__ x1q,
        const float* __restrict__ W2,
        const float* __restrict__ A, const float* __restrict__ B,
        float* __restrict__ x2) {
    __shared__ float sW[8 * 32];
    __shared__ float sAB[64];
    const int t = threadIdx.x;
    if (t < 64) ((float4*)sW)[t] = ((const float4*)W2)[t];
    if (t < 32) { sAB[t] = A[t]; sAB[32 + t] = B[t]; }
    __syncthreads();

    const int row = blockIdx.x * 256 + t;
    const bool valid = row < NVV;
    const int r = valid ? row : NVV - 1;
    float v[32];
    #pragma unroll
    for (int k4 = 0; k4 < 8; ++k4) {
        const float4 u = x1q[(size_t)k4 * NVV + r];
        const float4 a4 = *(const float4*)&sAB[k4 * 4];
        const float4 b4 = *(const float4*)&sAB[32 + k4 * 4];
        v[4 * k4 + 0] = fmaxf(fmaf(u.x, a4.x, b4.x), 0.f);
        v[4 * k4 + 1] = fmaxf(fmaf(u.y, a4.y, b4.y), 0.f);
        v[4 * k4 + 2] = fmaxf(fmaf(u.z, a4.z, b4.z), 0.f);
        v[4 * k4 + 3] = fmaxf(fmaf(u.w, a4.w, b4.w), 0.f);
    }
    #pragma unroll
    for (int jq = 0; jq < 2; ++jq) {
        float a0 = 0.f, a1 = 0.f, a2 = 0.f, a3 = 0.f;
        #pragma unroll
        for (int k4 = 0; k4 < 8; ++k4) {
            const float4 w0 = *(const float4*)&sW[(jq * 4 + 0) * 32 + k4 * 4];
            const float4 w1 = *(const float4*)&sW[(jq * 4 + 1) * 32 + k4 * 4];
            const float4 w2 = *(const float4*)&sW[(jq * 4 + 2) * 32 + k4 * 4];
            const float4 w3 = *(const float4*)&sW[(jq * 4 + 3) * 32 + k4 * 4];
            const float v0 = v[4 * k4], v1 = v[4 * k4 + 1], v2 = v[4 * k4 + 2], v3 = v[4 * k4 + 3];
            a0 = fmaf(v0, w0.x, fmaf(v1, w0.y, fmaf(v2, w0.z, fmaf(v3, w0.w, a0))));
            a1 = fmaf(v0, w1.x, fmaf(v1, w1.y, fmaf(v2, w1.z, fmaf(v3, w1.w, a1))));
            a2 = fmaf(v0, w2.x, fmaf(v1, w2.y, fmaf(v2, w2.z, fmaf(v3, w2.w, a2))));
            a3 = fmaf(v0, w3.x, fmaf(v1, w3.y, fmaf(v2, w3.z, fmaf(v3, w3.w, a3))));
        }
        if (valid) *(float4*)(x2 + (size_t)row * 8 + jq * 4) = make_float4(a0, a1, a2, a3);
    }
}

// ---------------------------------------------------------------------------
// K5: per-position gather + max-normalize + delta weights + classify via proj.
// ---------------------------------------------------------------------------
__global__ __launch_bounds__(256, 4) void k_final(const int* __restrict__ idx,
        const float* __restrict__ bary, const float* __restrict__ x2,
        const float* __restrict__ proj, const float* __restrict__ gamma,
        const float* __restrict__ beta, const float* __restrict__ dWw,
        const float* __restrict__ dWb, const float* __restrict__ clsb,
        float* __restrict__ out) {
    const int p = blockIdx.x * 256 + threadIdx.x;
    if (p >= PCNT) return;
    const int4 iv = *(const int4*)(idx + (size_t)p * 4);
    const float4 bv = *(const float4*)(bary + (size_t)p * 4);
    const int ids[4] = {iv.x, iv.y, iv.z, iv.w};
    const float bb[4] = {bv.x, bv.y, bv.z, bv.w};
    float g[4][8];
    #pragma unroll
    for (int vtx = 0; vtx < 4; ++vtx) {
        const float* s = x2 + (size_t)ids[vtx] * 8;
        const float4 u0 = *(const float4*)(s);
        const float4 u1 = *(const float4*)(s + 4);
        g[vtx][0] = u0.x; g[vtx][1] = u0.y; g[vtx][2] = u0.z; g[vtx][3] = u0.w;
        g[vtx][4] = u1.x; g[vtx][5] = u1.y; g[vtx][6] = u1.z; g[vtx][7] = u1.w;
    }
    float sub[9];
    #pragma unroll
    for (int j = 0; j < 8; ++j) {
        const float mx = fmaxf(fmaxf(g[0][j], g[1][j]), fmaxf(g[2][j], g[3][j]));
        sub[j] = fmaf(gamma[j], mx, beta[j]);
    }
    {
        const float mx8 = fmaxf(fmaxf(bb[0], bb[1]), fmaxf(bb[2], bb[3]));
        sub[8] = fmaf(gamma[8], mx8, beta[8]);
    }
    float wv4[4];
    #pragma unroll
    for (int vtx = 0; vtx < 4; ++vtx) {
        float dw = dWb[0];
        #pragma unroll
        for (int j = 0; j < 8; ++j) dw = fmaf(g[vtx][j] - sub[j], dWw[j], dw);
        dw = fmaf(bb[vtx] - sub[8], dWw[8], dw);
        wv4[vtx] = bb[vtx] + dw;
    }
    float acc[20];
    #pragma unroll
    for (int c = 0; c < 20; ++c) acc[c] = clsb[c];
    #pragma unroll
    for (int vtx = 0; vtx < 4; ++vtx) {
        const float* pr = proj + (size_t)ids[vtx] * 20;
        const float wgt = wv4[vtx];
        #pragma unroll
        for (int cq = 0; cq < 5; ++cq) {
            const float4 u = *(const float4*)(pr + cq * 4);
            acc[cq * 4 + 0] = fmaf(wgt, u.x, acc[cq * 4 + 0]);
            acc[cq * 4 + 1] = fmaf(wgt, u.y, acc[cq * 4 + 1]);
            acc[cq * 4 + 2] = fmaf(wgt, u.z, acc[cq * 4 + 2]);
            acc[cq * 4 + 3] = fmaf(wgt, u.w, acc[cq * 4 + 3]);
        }
    }
    float* o = out + (size_t)p * 20;
    #pragma unroll
    for (int cq = 0; cq < 5; ++cq)
        *(float4*)(o + cq * 4) = make_float4(acc[cq * 4 + 0], acc[cq * 4 + 1],
                                             acc[cq * 4 + 2], acc[cq * 4 + 3]);
}

// ---------------------------------------------------------------------------
extern "C" void kernel_launch(void* const* d_in, const int* in_sizes, int n_in,
                              void* d_out, int out_size, void* d_ws, size_t ws_size,
                              hipStream_t stream) {
    const float* lv   = (const float*)d_in[0];
    // d_in[1] = positions — unused by the reference
    const int*   idx  = (const int*)d_in[2];
    const float* bary = (const float*)d_in[3];
    const float* gn0w = (const float*)d_in[4];
    const float* gn0b = (const float*)d_in[5];
    const float* W0   = (const float*)d_in[6];
    const float* gn1w = (const float*)d_in[7];
    const float* gn1b = (const float*)d_in[8];
    const float* W1   = (const float*)d_in[9];
    const float* gn2w = (const float*)d_in[10];
    const float* gn2b = (const float*)d_in[11];
    const float* W2   = (const float*)d_in[12];
    const float* gamma= (const float*)d_in[13];
    const float* beta = (const float*)d_in[14];
    const float* dWw  = (const float*)d_in[15];
    const float* dWb  = (const float*)d_in[16];
    const float* clsW = (const float*)d_in[17];
    const float* clsb = (const float*)d_in[18];
    float* out = (float*)d_out;

    float* w = (float*)d_ws;
    float* rep0 = w;                  // 8*64
    float* rep1 = w + 512;            // 8*64
    float* rep2 = w + 1024;           // 8*64
    float* A0 = w + 1536; float* B0 = w + 1600;
    float* A1 = w + 1664; float* B1 = w + 1728;
    float* A2 = w + 1792; float* B2 = w + 1856;
    float*  proj = w + 2048;                         // NV*20 floats
    float4* x0q  = (float4*)(proj + (size_t)NVV * 20);   // 16*NV float4
    float4* x1q  = x0q + (size_t)16 * NVV;               // 8*NV float4
    float*  x2   = (float*)x0q;                          // reuse x0q after K3

    hipMemsetAsync(w, 0, 1536 * sizeof(float), stream);
    k_stats0<<<512, 256, 0, stream>>>(lv, rep0);
    k_finalize<<<1, 64, 0, stream>>>(rep0, gn0w, gn0b, A0, B0, 64, 1.f / (NVV * 2.f));
    k_stage0<<<1172, 256, 0, stream>>>(lv, W0, clsW, A0, B0, x0q, proj, rep1);
    k_finalize<<<1, 64, 0, stream>>>(rep1, gn1w, gn1b, A1, B1, 64, 1.f / (NVV * 2.f));
    k_stage1<<<1172, 256, 0, stream>>>(x0q, W1, A1, B1, x1q, rep2);
    k_finalize<<<1, 32, 0, stream>>>(rep2, gn2w, gn2b, A2, B2, 32, 1.f / (float)NVV);
    k_stage2<<<1172, 256, 0, stream>>>(x1q, W2, A2, B2, x2);
    k_final<<<1954, 256, 0, stream>>>(idx, bary, x2, proj, gamma, beta, dWw, dWb, clsb, out);
}